// Round 6
// baseline (775.159 us; speedup 1.0000x reference)
//
#include <hip/hip_runtime.h>
#include <hip/hip_bf16.h>
#include <hip/hip_fp16.h>
#include <math.h>

// Problem constants (match reference)
#define NNODES 100000
#define NEDGES 1600000
#define DH 128
#define DOUT 40
#define EPSBN 1e-5f
// CSR fill binning: bucket = dst / NPB, bucket region in csr is contiguous
#define NPB 25
#define NBUCK 4000   // ceil(100000/25)

// ---------------- degree / CSR build ----------------

__global__ void k_zero_counts(int* __restrict__ counts) {
    int i = blockIdx.x * blockDim.x + threadIdx.x;
    if (i < NNODES) counts[i] = 0;
}

__global__ void k_count(const int* __restrict__ ei, int* __restrict__ counts) {
    int e = blockIdx.x * blockDim.x + threadIdx.x;
    if (e < NEDGES) atomicAdd(&counts[ei[NEDGES + e]], 1);
}

__global__ void k_dinv(const int* __restrict__ counts, float* __restrict__ dinv) {
    int i = blockIdx.x * blockDim.x + threadIdx.x;
    if (i < NNODES) dinv[i] = 1.0f / sqrtf((float)counts[i] + 1.0f);
}

// per-block exclusive scan of counts -> row_start, block totals -> blockSums
__global__ void k_scan1(const int* __restrict__ counts, int* __restrict__ row_start,
                        int* __restrict__ blockSums) {
    __shared__ int s[256];
    int t = threadIdx.x;
    int g = blockIdx.x * 256 + t;
    int v = (g < NNODES) ? counts[g] : 0;
    s[t] = v;
    __syncthreads();
    for (int off = 1; off < 256; off <<= 1) {
        int x = (t >= off) ? s[t - off] : 0;
        __syncthreads();
        s[t] += x;
        __syncthreads();
    }
    if (g < NNODES) row_start[g] = s[t] - v;   // exclusive
    if (t == 255) blockSums[blockIdx.x] = s[255];
}

__global__ void k_scan2(int* __restrict__ blockSums, int nb) {
    __shared__ int s[512];
    int t = threadIdx.x;
    int v = (t < nb) ? blockSums[t] : 0;
    s[t] = v;
    __syncthreads();
    for (int off = 1; off < 512; off <<= 1) {
        int x = (t >= off) ? s[t - off] : 0;
        __syncthreads();
        s[t] += x;
        __syncthreads();
    }
    if (t < nb) blockSums[t] = s[t] - v;       // exclusive
}

__global__ void k_scan3(int* __restrict__ row_start, const int* __restrict__ blockSums,
                        int* __restrict__ cursor) {
    int g = blockIdx.x * 256 + threadIdx.x;
    if (g < NNODES) {
        int r = row_start[g] + blockSums[blockIdx.x];
        row_start[g] = r;
        cursor[g] = r;
    }
}

// bucket cursors: bucket b owns csr region [row_start[b*NPB], row_start[(b+1)*NPB])
__global__ void k_binit(const int* __restrict__ row_start, int* __restrict__ bcur) {
    int b = blockIdx.x * 256 + threadIdx.x;
    if (b < NBUCK) bcur[b] = row_start[b * NPB];
}

// pass 1: append {src,dst} into the dst's bucket region (dense line fills, ~1x write amp)
__global__ void k_fill1(const int* __restrict__ ei, int* __restrict__ bcur,
                        int2* __restrict__ tmp) {
    int e = blockIdx.x * blockDim.x + threadIdx.x;
    if (e >= NEDGES) return;
    int src = ei[e];
    int dst = ei[NEDGES + e];
    int p = atomicAdd(&bcur[dst / NPB], 1);
    tmp[p] = make_int2(src, dst);
}

// pass 2: sequential read of bucket-ordered tmp; final scatter stays within the
// ~3.2KB bucket region (L2-absorbed). w recomputed from L2-resident dinv.
__global__ void k_fill2(const int2* __restrict__ tmp, const float* __restrict__ dinv,
                        int* __restrict__ cursor, int2* __restrict__ csr) {
    int e = blockIdx.x * blockDim.x + threadIdx.x;
    if (e >= NEDGES) return;
    int2 t = tmp[e];
    float w = dinv[t.x] * dinv[t.y];
    int p = atomicAdd(&cursor[t.y], 1);
    csr[p] = make_int2(t.x, __float_as_int(w));
}

// ---------------- GEMM: out16[N][128] = act(A)[N][128] @ W[128][128], fp16 out ----

template <bool BN>
__global__ __launch_bounds__(256) void k_gemm128(const float* __restrict__ A,
                                                 const float* __restrict__ W,
                                                 __half* __restrict__ out,
                                                 const float* __restrict__ scale,
                                                 const float* __restrict__ shift) {
    const int BM = 64, BK = 32;
    __shared__ float As[BK][68];
    __shared__ float Bs[BK][128];
    int t = threadIdx.x;
    int tx = t & 15, ty = t >> 4;
    int r0 = blockIdx.x * BM;

    float acc[4][8];
#pragma unroll
    for (int i = 0; i < 4; i++)
#pragma unroll
        for (int j = 0; j < 8; j++) acc[i][j] = 0.0f;

    for (int k0 = 0; k0 < 128; k0 += BK) {
#pragma unroll
        for (int u = 0; u < 2; u++) {
            int idx = t + u * 256;
            int row = idx >> 3, c4 = idx & 7;
            int gr = r0 + row;
            float4 v = make_float4(0.f, 0.f, 0.f, 0.f);
            if (gr < NNODES)
                v = *reinterpret_cast<const float4*>(&A[(size_t)gr * 128 + k0 + c4 * 4]);
            if (BN) {
                int kc = k0 + c4 * 4;
                v.x = fmaxf(fmaf(v.x, scale[kc + 0], shift[kc + 0]), 0.f);
                v.y = fmaxf(fmaf(v.y, scale[kc + 1], shift[kc + 1]), 0.f);
                v.z = fmaxf(fmaf(v.z, scale[kc + 2], shift[kc + 2]), 0.f);
                v.w = fmaxf(fmaf(v.w, scale[kc + 3], shift[kc + 3]), 0.f);
            }
            As[c4 * 4 + 0][row] = v.x;
            As[c4 * 4 + 1][row] = v.y;
            As[c4 * 4 + 2][row] = v.z;
            As[c4 * 4 + 3][row] = v.w;
        }
#pragma unroll
        for (int u = 0; u < 4; u++) {
            int idx = t + u * 256;
            int k = idx >> 5, c4 = idx & 31;
            *reinterpret_cast<float4*>(&Bs[k][c4 * 4]) =
                *reinterpret_cast<const float4*>(&W[(size_t)(k0 + k) * 128 + c4 * 4]);
        }
        __syncthreads();
#pragma unroll
        for (int k = 0; k < BK; k++) {
            float a[4];
            *reinterpret_cast<float4*>(a) = *reinterpret_cast<const float4*>(&As[k][ty * 4]);
            float b[8];
#pragma unroll
            for (int j = 0; j < 8; j++) b[j] = Bs[k][tx * 8 + j];
#pragma unroll
            for (int i = 0; i < 4; i++)
#pragma unroll
                for (int j = 0; j < 8; j++) acc[i][j] = fmaf(a[i], b[j], acc[i][j]);
        }
        __syncthreads();
    }
#pragma unroll
    for (int i = 0; i < 4; i++) {
        int gr = r0 + ty * 4 + i;
        if (gr >= NNODES) continue;
        __half hv[8] __attribute__((aligned(16)));
#pragma unroll
        for (int j = 0; j < 8; j++) hv[j] = __float2half_rn(acc[i][j]);
        *reinterpret_cast<uint4*>(&out[(size_t)gr * 128 + tx * 8]) =
            *reinterpret_cast<const uint4*>(hv);
    }
}

// ---------------- GEMM 128->40 (fp32 in) with bias + log_softmax epilogue -------

__global__ __launch_bounds__(256) void k_gemm40_lsm(const float* __restrict__ A,
                                                    const float* __restrict__ W,
                                                    const float* __restrict__ bias,
                                                    float* __restrict__ out) {
    const int BM = 64, BK = 32;
    __shared__ float As[BK][68];
    __shared__ float Bs[BK][48];
    int t = threadIdx.x;
    int tx = t & 15, ty = t >> 4;
    int r0 = blockIdx.x * BM;

    float acc[4][3];
#pragma unroll
    for (int i = 0; i < 4; i++)
#pragma unroll
        for (int j = 0; j < 3; j++) acc[i][j] = 0.0f;

    for (int k0 = 0; k0 < 128; k0 += BK) {
#pragma unroll
        for (int u = 0; u < 2; u++) {
            int idx = t + u * 256;
            int row = idx >> 3, c4 = idx & 7;
            int gr = r0 + row;
            float4 v = make_float4(0.f, 0.f, 0.f, 0.f);
            if (gr < NNODES)
                v = *reinterpret_cast<const float4*>(&A[(size_t)gr * 128 + k0 + c4 * 4]);
            As[c4 * 4 + 0][row] = v.x;
            As[c4 * 4 + 1][row] = v.y;
            As[c4 * 4 + 2][row] = v.z;
            As[c4 * 4 + 3][row] = v.w;
        }
        for (int idx = t; idx < BK * 48; idx += 256) {
            int k = idx / 48, c = idx % 48;
            Bs[k][c] = (c < DOUT) ? W[(size_t)(k0 + k) * DOUT + c] : 0.f;
        }
        __syncthreads();
#pragma unroll
        for (int k = 0; k < BK; k++) {
            float a[4];
            *reinterpret_cast<float4*>(a) = *reinterpret_cast<const float4*>(&As[k][ty * 4]);
            float b[3];
#pragma unroll
            for (int j = 0; j < 3; j++) b[j] = Bs[k][tx * 3 + j];
#pragma unroll
            for (int i = 0; i < 4; i++)
#pragma unroll
                for (int j = 0; j < 3; j++) acc[i][j] = fmaf(a[i], b[j], acc[i][j]);
        }
        __syncthreads();
    }
    // epilogue: +bias, then per-row log_softmax (row split across 16 lanes of same ty)
#pragma unroll
    for (int i = 0; i < 4; i++) {
        int gr = r0 + ty * 4 + i;
        float v[3];
        float m = -1e30f;
#pragma unroll
        for (int j = 0; j < 3; j++) {
            int c = tx * 3 + j;
            v[j] = (c < DOUT) ? acc[i][j] + bias[c] : -1e30f;
            m = fmaxf(m, v[j]);
        }
#pragma unroll
        for (int off = 8; off; off >>= 1) m = fmaxf(m, __shfl_xor(m, off));
        float es = 0.f;
#pragma unroll
        for (int j = 0; j < 3; j++)
            if (tx * 3 + j < DOUT) es += expf(v[j] - m);
#pragma unroll
        for (int off = 8; off; off >>= 1) es += __shfl_xor(es, off);
        float lse = m + logf(es);
        if (gr < NNODES) {
#pragma unroll
            for (int j = 0; j < 3; j++) {
                int c = tx * 3 + j;
                if (c < DOUT) out[(size_t)gr * DOUT + c] = v[j] - lse;
            }
        }
    }
}

// ---------------- aggregation (pull via CSR), fp16 rows ----------------
// One wave per dst row. 4 edge slots (16 lanes each); each lane loads uint4 =
// 8 halves (16B) -> 16 lanes cover the 256B fp16 row. 8 edges in flight per
// iteration (2 per slot). Quarter-wave results combined via shfl_xor(16|32).
// out32[n] = act(h[n])*dinv^2 + (bias) + sum act(h[src])*w ; optional raw fp16 copy.

template <bool BN>
__device__ __forceinline__ void accum8(float (&acc)[8], uint4 raw, float w,
                                       const float (&sc)[8], const float (&sh)[8]) {
    const __half2* hp = reinterpret_cast<const __half2*>(&raw);
#pragma unroll
    for (int p = 0; p < 4; p++) {
        float2 f = __half22float2(hp[p]);
        if (BN) {
            f.x = fmaxf(fmaf(f.x, sc[2 * p + 0], sh[2 * p + 0]), 0.f);
            f.y = fmaxf(fmaf(f.y, sc[2 * p + 1], sh[2 * p + 1]), 0.f);
        }
        acc[2 * p + 0] = fmaf(f.x, w, acc[2 * p + 0]);
        acc[2 * p + 1] = fmaf(f.y, w, acc[2 * p + 1]);
    }
}

template <bool BN, bool BIAS, bool W16>
__global__ __launch_bounds__(256) void k_aggh(const __half* __restrict__ h,
                                              const float* __restrict__ dinv,
                                              const int* __restrict__ row_start,
                                              const int* __restrict__ counts,
                                              const int2* __restrict__ csr,
                                              const float* __restrict__ bias,
                                              const float* __restrict__ scale,
                                              const float* __restrict__ shift,
                                              float* __restrict__ out,
                                              __half* __restrict__ out16) {
    int wid = threadIdx.x >> 6, lane = threadIdx.x & 63;
    int n = blockIdx.x * 4 + wid;
    if (n >= NNODES) return;
    int slot = lane >> 4;          // 0..3 edge slot
    int c0 = (lane & 15) * 8;      // this lane's 8-column base

    float sc[8], sh[8];
    if (BN) {
        *reinterpret_cast<float4*>(&sc[0]) = *reinterpret_cast<const float4*>(&scale[c0]);
        *reinterpret_cast<float4*>(&sc[4]) = *reinterpret_cast<const float4*>(&scale[c0 + 4]);
        *reinterpret_cast<float4*>(&sh[0]) = *reinterpret_cast<const float4*>(&shift[c0]);
        *reinterpret_cast<float4*>(&sh[4]) = *reinterpret_cast<const float4*>(&shift[c0 + 4]);
    }

    float acc[8];
#pragma unroll
    for (int j = 0; j < 8; j++) acc[j] = 0.f;

    // self-loop term on slot 0
    if (slot == 0) {
        float di = dinv[n];
        float d2 = di * di;
        uint4 raw = *reinterpret_cast<const uint4*>(&h[(size_t)n * 128 + c0]);
        const __half2* hp = reinterpret_cast<const __half2*>(&raw);
#pragma unroll
        for (int p = 0; p < 4; p++) {
            float2 f = __half22float2(hp[p]);
            if (BN) {
                f.x = fmaxf(fmaf(f.x, sc[2 * p + 0], sh[2 * p + 0]), 0.f);
                f.y = fmaxf(fmaf(f.y, sc[2 * p + 1], sh[2 * p + 1]), 0.f);
            }
            acc[2 * p + 0] = f.x * d2;
            acc[2 * p + 1] = f.y * d2;
        }
        if (BIAS) {
            float bv[8];
            *reinterpret_cast<float4*>(&bv[0]) = *reinterpret_cast<const float4*>(&bias[c0]);
            *reinterpret_cast<float4*>(&bv[4]) = *reinterpret_cast<const float4*>(&bias[c0 + 4]);
#pragma unroll
            for (int j = 0; j < 8; j++) acc[j] += bv[j];
        }
    }

    int s = row_start[n], len = counts[n];
    int i = 0;
    for (; i + 8 <= len; i += 8) {
        int2 e0 = csr[s + i + slot];
        int2 e1 = csr[s + i + 4 + slot];
        uint4 r0 = *reinterpret_cast<const uint4*>(&h[(size_t)e0.x * 128 + c0]);
        uint4 r1 = *reinterpret_cast<const uint4*>(&h[(size_t)e1.x * 128 + c0]);
        accum8<BN>(acc, r0, __int_as_float(e0.y), sc, sh);
        accum8<BN>(acc, r1, __int_as_float(e1.y), sc, sh);
    }
    if (i < len) {   // masked tail: idx 0 / weight 0 (h[0] is valid memory)
        int i0 = i + slot, i1 = i + 4 + slot;
        int2 e0 = (i0 < len) ? csr[s + i0] : make_int2(0, 0);
        int2 e1 = (i1 < len) ? csr[s + i1] : make_int2(0, 0);
        uint4 r0 = *reinterpret_cast<const uint4*>(&h[(size_t)e0.x * 128 + c0]);
        uint4 r1 = *reinterpret_cast<const uint4*>(&h[(size_t)e1.x * 128 + c0]);
        accum8<BN>(acc, r0, __int_as_float(e0.y), sc, sh);
        accum8<BN>(acc, r1, __int_as_float(e1.y), sc, sh);
    }

    // combine 4 slots; all lanes end with the full sum
#pragma unroll
    for (int j = 0; j < 8; j++) {
        acc[j] += __shfl_xor(acc[j], 16);
        acc[j] += __shfl_xor(acc[j], 32);
    }
    if (slot == 0) {
        *reinterpret_cast<float4*>(&out[(size_t)n * 128 + c0]) =
            make_float4(acc[0], acc[1], acc[2], acc[3]);
        *reinterpret_cast<float4*>(&out[(size_t)n * 128 + c0 + 4]) =
            make_float4(acc[4], acc[5], acc[6], acc[7]);
        if (W16) {
            __half hv[8] __attribute__((aligned(16)));
#pragma unroll
            for (int j = 0; j < 8; j++) hv[j] = __float2half_rn(acc[j]);
            *reinterpret_cast<uint4*>(&out16[(size_t)n * 128 + c0]) =
                *reinterpret_cast<const uint4*>(hv);
        }
    }
}

// ---------------- BatchNorm statistics (float4 loads) ----------------

__global__ void k_zero_stats(double* __restrict__ colsum) {
    int t = threadIdx.x;
    if (t < 256) colsum[t] = 0.0;
}

__global__ __launch_bounds__(256) void k_stats(const float* __restrict__ buf,
                                               double* __restrict__ colsum) {
    int t = threadIdx.x;
    int cb = (t & 31) * 4;          // this thread's 4-column base (stride 256 == 0 mod 32)
    float4 s = make_float4(0.f, 0.f, 0.f, 0.f);
    float4 q = make_float4(0.f, 0.f, 0.f, 0.f);
    const float4* b4 = reinterpret_cast<const float4*>(buf);
    const long total4 = (long)NNODES * 32;
    for (long g = (long)blockIdx.x * 256 + t; g < total4; g += (long)gridDim.x * 256) {
        float4 v = b4[g];
        s.x += v.x; q.x += v.x * v.x;
        s.y += v.y; q.y += v.y * v.y;
        s.z += v.z; q.z += v.z * v.z;
        s.w += v.w; q.w += v.w * v.w;
    }
    __shared__ float ls[128][9];    // [col][group], pad 9 avoids bank conflicts
    __shared__ float lq[128][9];
    int grp = t >> 5;               // 8 groups of 32 threads share each col-base
    ls[cb + 0][grp] = s.x; lq[cb + 0][grp] = q.x;
    ls[cb + 1][grp] = s.y; lq[cb + 1][grp] = q.y;
    ls[cb + 2][grp] = s.z; lq[cb + 2][grp] = q.z;
    ls[cb + 3][grp] = s.w; lq[cb + 3][grp] = q.w;
    __syncthreads();
    if (t < 128) {
        double ds = 0.0, dq = 0.0;
#pragma unroll
        for (int j = 0; j < 8; j++) { ds += ls[t][j]; dq += lq[t][j]; }
        atomicAdd(&colsum[t], ds);
        atomicAdd(&colsum[128 + t], dq);
    }
}

__global__ void k_bn_finalize(const double* __restrict__ colsum, const float* __restrict__ g,
                              const float* __restrict__ be, float* __restrict__ scale,
                              float* __restrict__ shift) {
    int c = threadIdx.x;
    if (c >= 128) return;
    double mu = colsum[c] / (double)NNODES;
    double var = colsum[128 + c] / (double)NNODES - mu * mu;
    float sc = g[c] * (1.0f / sqrtf((float)var + EPSBN));
    scale[c] = sc;
    shift[c] = be[c] - (float)mu * sc;
}

// ---------------- launch ----------------

extern "C" void kernel_launch(void* const* d_in, const int* in_sizes, int n_in,
                              void* d_out, int out_size, void* d_ws, size_t ws_size,
                              hipStream_t stream) {
    const float* x  = (const float*)d_in[0];
    const int* ei   = (const int*)d_in[1];
    const float* W1 = (const float*)d_in[2];
    const float* b1 = (const float*)d_in[3];
    const float* g1 = (const float*)d_in[4];
    const float* be1 = (const float*)d_in[5];
    const float* W2 = (const float*)d_in[6];
    const float* b2 = (const float*)d_in[7];
    const float* g2 = (const float*)d_in[8];
    const float* be2 = (const float*)d_in[9];
    const float* Wf = (const float*)d_in[10];
    const float* bf = (const float*)d_in[11];
    float* out = (float*)d_out;

    char* ws = (char*)d_ws;
    int*    counts    = (int*)(ws + 0);
    int*    row_start = (int*)(ws + 512ull * 1024);
    int*    cursor    = (int*)(ws + 1024ull * 1024);
    float*  dinv      = (float*)(ws + 1536ull * 1024);
    int*    blockSums = (int*)(ws + 2048ull * 1024);
    double* colsum    = (double*)(ws + 2304ull * 1024);
    float*  scale     = (float*)(ws + 2368ull * 1024);
    float*  shift     = (float*)(ws + 2372ull * 1024);
    int*    bcur      = (int*)(ws + 2400ull * 1024);          // 16 KB
    int2*   csr       = (int2*)(ws + 3ull * 1024 * 1024);     // 12.8 MB
    __half* h16       = (__half*)(ws + 16ull * 1024 * 1024);  // 25.6 MB (h1, then h2)
    __half* z16       = (__half*)(ws + 42ull * 1024 * 1024);  // 25.6 MB (raw z2 copy)
    float*  zbuf      = (float*)(ws + 68ull * 1024 * 1024);   // 51.2 MB (z1 -> z2 -> a3)
    int2*   tmp       = (int2*)(ws + 68ull * 1024 * 1024);    // aliases zbuf (dead before agg1)

    const int NB_N = (NNODES + 255) / 256;     // 391
    const int NB_E = (NEDGES + 255) / 256;     // 6250
    const int NB_G = (NNODES + 63) / 64;       // 1563 (gemm)
    const int NB_A = (NNODES + 3) / 4;         // 25000 (agg)
    const int NB_B = (NBUCK + 255) / 256;      // 16

    // CSR build (two-level binned scatter: ~1x write amplification)
    hipLaunchKernelGGL(k_zero_counts, dim3(NB_N), dim3(256), 0, stream, counts);
    hipLaunchKernelGGL(k_count, dim3(NB_E), dim3(256), 0, stream, ei, counts);
    hipLaunchKernelGGL(k_dinv, dim3(NB_N), dim3(256), 0, stream, counts, dinv);
    hipLaunchKernelGGL(k_scan1, dim3(NB_N), dim3(256), 0, stream, counts, row_start, blockSums);
    hipLaunchKernelGGL(k_scan2, dim3(1), dim3(512), 0, stream, blockSums, NB_N);
    hipLaunchKernelGGL(k_scan3, dim3(NB_N), dim3(256), 0, stream, row_start, blockSums, cursor);
    hipLaunchKernelGGL(k_binit, dim3(NB_B), dim3(256), 0, stream, row_start, bcur);
    hipLaunchKernelGGL(k_fill1, dim3(NB_E), dim3(256), 0, stream, ei, bcur, tmp);
    hipLaunchKernelGGL(k_fill2, dim3(NB_E), dim3(256), 0, stream, tmp, dinv, cursor, csr);

    // conv1: gemm (fp16 out) + aggregate(+b1) -> z1 (fp32)
    hipLaunchKernelGGL((k_gemm128<false>), dim3(NB_G), dim3(256), 0, stream,
                       x, W1, h16, (const float*)nullptr, (const float*)nullptr);
    hipLaunchKernelGGL((k_aggh<false, true, false>), dim3(NB_A), dim3(256), 0, stream,
                       h16, dinv, row_start, counts, csr, b1,
                       (const float*)nullptr, (const float*)nullptr, zbuf, (__half*)nullptr);
    // BN1 stats over z1
    hipLaunchKernelGGL(k_zero_stats, dim3(1), dim3(256), 0, stream, colsum);
    hipLaunchKernelGGL(k_stats, dim3(1024), dim3(256), 0, stream, zbuf, colsum);
    hipLaunchKernelGGL(k_bn_finalize, dim3(1), dim3(128), 0, stream, colsum, g1, be1, scale, shift);

    // conv2: gemm (BN1+ReLU fused on A-load, fp16 out) + aggregate(+b2) -> z2 (fp32 + fp16 raw)
    hipLaunchKernelGGL((k_gemm128<true>), dim3(NB_G), dim3(256), 0, stream,
                       zbuf, W2, h16, scale, shift);
    hipLaunchKernelGGL((k_aggh<false, true, true>), dim3(NB_A), dim3(256), 0, stream,
                       h16, dinv, row_start, counts, csr, b2,
                       (const float*)nullptr, (const float*)nullptr, zbuf, z16);
    // BN2 stats over z2
    hipLaunchKernelGGL(k_zero_stats, dim3(1), dim3(256), 0, stream, colsum);
    hipLaunchKernelGGL(k_stats, dim3(1024), dim3(256), 0, stream, zbuf, colsum);
    hipLaunchKernelGGL(k_bn_finalize, dim3(1), dim3(128), 0, stream, colsum, g2, be2, scale, shift);

    // conv3 restructured: agg(act2) first (BN2+ReLU fused on fp16 gather), then GEMM->40+lsm.
    // agg(act @ Wf) == agg(act) @ Wf since aggregation is linear.
    hipLaunchKernelGGL((k_aggh<true, false, false>), dim3(NB_A), dim3(256), 0, stream,
                       z16, dinv, row_start, counts, csr, (const float*)nullptr,
                       scale, shift, zbuf, (__half*)nullptr);
    hipLaunchKernelGGL(k_gemm40_lsm, dim3(NB_G), dim3(256), 0, stream, zbuf, Wf, bf, out);
}

// Round 7
// 629.666 us; speedup vs baseline: 1.2311x; 1.2311x over previous
//
#include <hip/hip_runtime.h>
#include <hip/hip_bf16.h>
#include <hip/hip_fp16.h>
#include <math.h>

// Problem constants (match reference)
#define NNODES 100000
#define NEDGES 1600000
#define DH 128
#define DOUT 40
#define EPSBN 1e-5f
// counting-sort fill: bucket = dst >> FB_SH (256 nodes/bucket)
#define FB_SH 8
#define FB_NB ((NNODES + 255) >> 8)   // 391 buckets

// ---------------- degree / CSR build ----------------

__global__ void k_zero_counts(int* __restrict__ counts) {
    int i = blockIdx.x * blockDim.x + threadIdx.x;
    if (i < NNODES) counts[i] = 0;
}

__global__ void k_count(const int* __restrict__ ei, int* __restrict__ counts) {
    int e = blockIdx.x * blockDim.x + threadIdx.x;
    if (e < NEDGES) atomicAdd(&counts[ei[NEDGES + e]], 1);
}

__global__ void k_dinv(const int* __restrict__ counts, float* __restrict__ dinv) {
    int i = blockIdx.x * blockDim.x + threadIdx.x;
    if (i < NNODES) dinv[i] = 1.0f / sqrtf((float)counts[i] + 1.0f);
}

// per-block exclusive scan of counts -> row_start, block totals -> blockSums
__global__ void k_scan1(const int* __restrict__ counts, int* __restrict__ row_start,
                        int* __restrict__ blockSums) {
    __shared__ int s[256];
    int t = threadIdx.x;
    int g = blockIdx.x * 256 + t;
    int v = (g < NNODES) ? counts[g] : 0;
    s[t] = v;
    __syncthreads();
    for (int off = 1; off < 256; off <<= 1) {
        int x = (t >= off) ? s[t - off] : 0;
        __syncthreads();
        s[t] += x;
        __syncthreads();
    }
    if (g < NNODES) row_start[g] = s[t] - v;   // exclusive
    if (t == 255) blockSums[blockIdx.x] = s[255];
}

__global__ void k_scan2(int* __restrict__ blockSums, int nb) {
    __shared__ int s[512];
    int t = threadIdx.x;
    int v = (t < nb) ? blockSums[t] : 0;
    s[t] = v;
    __syncthreads();
    for (int off = 1; off < 512; off <<= 1) {
        int x = (t >= off) ? s[t - off] : 0;
        __syncthreads();
        s[t] += x;
        __syncthreads();
    }
    if (t < nb) blockSums[t] = s[t] - v;       // exclusive
}

__global__ void k_scan3(int* __restrict__ row_start, const int* __restrict__ blockSums,
                        int* __restrict__ cursor) {
    int g = blockIdx.x * 256 + threadIdx.x;
    if (g < NNODES) {
        int r = row_start[g] + blockSums[blockIdx.x];
        row_start[g] = r;
        cursor[g] = r;
    }
}

// bucket cursors: bucket b's tmp region starts at row_start[b << FB_SH]
__global__ void k_binit(const int* __restrict__ row_start, int* __restrict__ bcur) {
    int b = blockIdx.x * 256 + threadIdx.x;
    if (b < FB_NB) bcur[b] = row_start[b << FB_SH];
}

// fill pass A: each WG owns a contiguous edge chunk. Count per bucket in LDS,
// reserve ONE contiguous private range per (WG,bucket), then scatter {src,dst}
// into it. Private ranges -> lines written by a single XCD -> ~1x write amp.
__global__ __launch_bounds__(256) void k_fillA(const int* __restrict__ ei,
                                               int* __restrict__ bcur,
                                               int2* __restrict__ tmp) {
    __shared__ int lcnt[FB_NB];
    __shared__ int lbase[FB_NB];
    int t = threadIdx.x;
    const int chunk = (NEDGES + gridDim.x - 1) / gridDim.x;
    int e0 = blockIdx.x * chunk;
    int e1 = min(e0 + chunk, NEDGES);
    for (int i = t; i < FB_NB; i += 256) lcnt[i] = 0;
    __syncthreads();
    for (int e = e0 + t; e < e1; e += 256)
        atomicAdd(&lcnt[ei[NEDGES + e] >> FB_SH], 1);
    __syncthreads();
    for (int b = t; b < FB_NB; b += 256) {
        int c = lcnt[b];
        lbase[b] = c ? atomicAdd(&bcur[b], c) : 0;
    }
    __syncthreads();
    for (int i = t; i < FB_NB; i += 256) lcnt[i] = 0;
    __syncthreads();
    for (int e = e0 + t; e < e1; e += 256) {
        int src = ei[e];
        int dst = ei[NEDGES + e];
        int b = dst >> FB_SH;
        int r = atomicAdd(&lcnt[b], 1);
        tmp[lbase[b] + r] = make_int2(src, dst);
    }
}

// fill pass B: ONE WG per bucket. Sequential read of the bucket's tmp region;
// exact-dst rank via LDS counters (all of this bucket's edges are here, so the
// LDS rank is globally correct -- no global atomics). Scatter stays within the
// bucket's ~32KB csr region on one XCD.
__global__ __launch_bounds__(256) void k_fillB(const int2* __restrict__ tmp,
                                               const int* __restrict__ row_start,
                                               const float* __restrict__ dinv,
                                               int2* __restrict__ csr) {
    __shared__ int lrank[1 << FB_SH];
    int t = threadIdx.x;
    int b = blockIdx.x;
    int n0 = b << FB_SH;
    int s = row_start[n0];
    int e = (((b + 1) << FB_SH) >= NNODES) ? NEDGES : row_start[(b + 1) << FB_SH];
    for (int i = t; i < (1 << FB_SH); i += 256) lrank[i] = 0;
    __syncthreads();
    for (int i = s + t; i < e; i += 256) {
        int2 sd = tmp[i];
        float w = dinv[sd.x] * dinv[sd.y];
        int r = atomicAdd(&lrank[sd.y - n0], 1);
        csr[row_start[sd.y] + r] = make_int2(sd.x, __float_as_int(w));
    }
}

// ---------------- GEMM: out16[N][128] = act(A)[N][128] @ W[128][128], fp16 out ----

template <bool BN>
__global__ __launch_bounds__(256) void k_gemm128(const float* __restrict__ A,
                                                 const float* __restrict__ W,
                                                 __half* __restrict__ out,
                                                 const float* __restrict__ scale,
                                                 const float* __restrict__ shift) {
    const int BM = 64, BK = 32;
    __shared__ float As[BK][68];
    __shared__ float Bs[BK][128];
    int t = threadIdx.x;
    int tx = t & 15, ty = t >> 4;
    int r0 = blockIdx.x * BM;

    float acc[4][8];
#pragma unroll
    for (int i = 0; i < 4; i++)
#pragma unroll
        for (int j = 0; j < 8; j++) acc[i][j] = 0.0f;

    for (int k0 = 0; k0 < 128; k0 += BK) {
#pragma unroll
        for (int u = 0; u < 2; u++) {
            int idx = t + u * 256;
            int row = idx >> 3, c4 = idx & 7;
            int gr = r0 + row;
            float4 v = make_float4(0.f, 0.f, 0.f, 0.f);
            if (gr < NNODES)
                v = *reinterpret_cast<const float4*>(&A[(size_t)gr * 128 + k0 + c4 * 4]);
            if (BN) {
                int kc = k0 + c4 * 4;
                v.x = fmaxf(fmaf(v.x, scale[kc + 0], shift[kc + 0]), 0.f);
                v.y = fmaxf(fmaf(v.y, scale[kc + 1], shift[kc + 1]), 0.f);
                v.z = fmaxf(fmaf(v.z, scale[kc + 2], shift[kc + 2]), 0.f);
                v.w = fmaxf(fmaf(v.w, scale[kc + 3], shift[kc + 3]), 0.f);
            }
            As[c4 * 4 + 0][row] = v.x;
            As[c4 * 4 + 1][row] = v.y;
            As[c4 * 4 + 2][row] = v.z;
            As[c4 * 4 + 3][row] = v.w;
        }
#pragma unroll
        for (int u = 0; u < 4; u++) {
            int idx = t + u * 256;
            int k = idx >> 5, c4 = idx & 31;
            *reinterpret_cast<float4*>(&Bs[k][c4 * 4]) =
                *reinterpret_cast<const float4*>(&W[(size_t)(k0 + k) * 128 + c4 * 4]);
        }
        __syncthreads();
#pragma unroll
        for (int k = 0; k < BK; k++) {
            float a[4];
            *reinterpret_cast<float4*>(a) = *reinterpret_cast<const float4*>(&As[k][ty * 4]);
            float b[8];
#pragma unroll
            for (int j = 0; j < 8; j++) b[j] = Bs[k][tx * 8 + j];
#pragma unroll
            for (int i = 0; i < 4; i++)
#pragma unroll
                for (int j = 0; j < 8; j++) acc[i][j] = fmaf(a[i], b[j], acc[i][j]);
        }
        __syncthreads();
    }
#pragma unroll
    for (int i = 0; i < 4; i++) {
        int gr = r0 + ty * 4 + i;
        if (gr >= NNODES) continue;
        __half hv[8] __attribute__((aligned(16)));
#pragma unroll
        for (int j = 0; j < 8; j++) hv[j] = __float2half_rn(acc[i][j]);
        *reinterpret_cast<uint4*>(&out[(size_t)gr * 128 + tx * 8]) =
            *reinterpret_cast<const uint4*>(hv);
    }
}

// ---------------- GEMM 128->40 (fp32 in) with bias + log_softmax epilogue -------

__global__ __launch_bounds__(256) void k_gemm40_lsm(const float* __restrict__ A,
                                                    const float* __restrict__ W,
                                                    const float* __restrict__ bias,
                                                    float* __restrict__ out) {
    const int BM = 64, BK = 32;
    __shared__ float As[BK][68];
    __shared__ float Bs[BK][48];
    int t = threadIdx.x;
    int tx = t & 15, ty = t >> 4;
    int r0 = blockIdx.x * BM;

    float acc[4][3];
#pragma unroll
    for (int i = 0; i < 4; i++)
#pragma unroll
        for (int j = 0; j < 3; j++) acc[i][j] = 0.0f;

    for (int k0 = 0; k0 < 128; k0 += BK) {
#pragma unroll
        for (int u = 0; u < 2; u++) {
            int idx = t + u * 256;
            int row = idx >> 3, c4 = idx & 7;
            int gr = r0 + row;
            float4 v = make_float4(0.f, 0.f, 0.f, 0.f);
            if (gr < NNODES)
                v = *reinterpret_cast<const float4*>(&A[(size_t)gr * 128 + k0 + c4 * 4]);
            As[c4 * 4 + 0][row] = v.x;
            As[c4 * 4 + 1][row] = v.y;
            As[c4 * 4 + 2][row] = v.z;
            As[c4 * 4 + 3][row] = v.w;
        }
        for (int idx = t; idx < BK * 48; idx += 256) {
            int k = idx / 48, c = idx % 48;
            Bs[k][c] = (c < DOUT) ? W[(size_t)(k0 + k) * DOUT + c] : 0.f;
        }
        __syncthreads();
#pragma unroll
        for (int k = 0; k < BK; k++) {
            float a[4];
            *reinterpret_cast<float4*>(a) = *reinterpret_cast<const float4*>(&As[k][ty * 4]);
            float b[3];
#pragma unroll
            for (int j = 0; j < 3; j++) b[j] = Bs[k][tx * 3 + j];
#pragma unroll
            for (int i = 0; i < 4; i++)
#pragma unroll
                for (int j = 0; j < 3; j++) acc[i][j] = fmaf(a[i], b[j], acc[i][j]);
        }
        __syncthreads();
    }
    // epilogue: +bias, then per-row log_softmax (row split across 16 lanes of same ty)
#pragma unroll
    for (int i = 0; i < 4; i++) {
        int gr = r0 + ty * 4 + i;
        float v[3];
        float m = -1e30f;
#pragma unroll
        for (int j = 0; j < 3; j++) {
            int c = tx * 3 + j;
            v[j] = (c < DOUT) ? acc[i][j] + bias[c] : -1e30f;
            m = fmaxf(m, v[j]);
        }
#pragma unroll
        for (int off = 8; off; off >>= 1) m = fmaxf(m, __shfl_xor(m, off));
        float es = 0.f;
#pragma unroll
        for (int j = 0; j < 3; j++)
            if (tx * 3 + j < DOUT) es += expf(v[j] - m);
#pragma unroll
        for (int off = 8; off; off >>= 1) es += __shfl_xor(es, off);
        float lse = m + logf(es);
        if (gr < NNODES) {
#pragma unroll
            for (int j = 0; j < 3; j++) {
                int c = tx * 3 + j;
                if (c < DOUT) out[(size_t)gr * DOUT + c] = v[j] - lse;
            }
        }
    }
}

// ---------------- aggregation (pull via CSR), fp16 rows ----------------
// One wave per dst row. 4 edge slots (16 lanes each); each lane loads uint4 =
// 8 halves (16B) -> 16 lanes cover the 256B fp16 row. 8 edges in flight per
// iteration (2 per slot). Quarter-wave results combined via shfl_xor(16|32).
// out32[n] = act(h[n])*dinv^2 + (bias) + sum act(h[src])*w ; optional raw fp16 copy.

template <bool BN>
__device__ __forceinline__ void accum8(float (&acc)[8], uint4 raw, float w,
                                       const float (&sc)[8], const float (&sh)[8]) {
    const __half2* hp = reinterpret_cast<const __half2*>(&raw);
#pragma unroll
    for (int p = 0; p < 4; p++) {
        float2 f = __half22float2(hp[p]);
        if (BN) {
            f.x = fmaxf(fmaf(f.x, sc[2 * p + 0], sh[2 * p + 0]), 0.f);
            f.y = fmaxf(fmaf(f.y, sc[2 * p + 1], sh[2 * p + 1]), 0.f);
        }
        acc[2 * p + 0] = fmaf(f.x, w, acc[2 * p + 0]);
        acc[2 * p + 1] = fmaf(f.y, w, acc[2 * p + 1]);
    }
}

template <bool BN, bool BIAS, bool W16>
__global__ __launch_bounds__(256) void k_aggh(const __half* __restrict__ h,
                                              const float* __restrict__ dinv,
                                              const int* __restrict__ row_start,
                                              const int* __restrict__ counts,
                                              const int2* __restrict__ csr,
                                              const float* __restrict__ bias,
                                              const float* __restrict__ scale,
                                              const float* __restrict__ shift,
                                              float* __restrict__ out,
                                              __half* __restrict__ out16) {
    int wid = threadIdx.x >> 6, lane = threadIdx.x & 63;
    int n = blockIdx.x * 4 + wid;
    if (n >= NNODES) return;
    int slot = lane >> 4;          // 0..3 edge slot
    int c0 = (lane & 15) * 8;      // this lane's 8-column base

    float sc[8], sh[8];
    if (BN) {
        *reinterpret_cast<float4*>(&sc[0]) = *reinterpret_cast<const float4*>(&scale[c0]);
        *reinterpret_cast<float4*>(&sc[4]) = *reinterpret_cast<const float4*>(&scale[c0 + 4]);
        *reinterpret_cast<float4*>(&sh[0]) = *reinterpret_cast<const float4*>(&shift[c0]);
        *reinterpret_cast<float4*>(&sh[4]) = *reinterpret_cast<const float4*>(&shift[c0 + 4]);
    }

    float acc[8];
#pragma unroll
    for (int j = 0; j < 8; j++) acc[j] = 0.f;

    // self-loop term on slot 0
    if (slot == 0) {
        float di = dinv[n];
        float d2 = di * di;
        uint4 raw = *reinterpret_cast<const uint4*>(&h[(size_t)n * 128 + c0]);
        const __half2* hp = reinterpret_cast<const __half2*>(&raw);
#pragma unroll
        for (int p = 0; p < 4; p++) {
            float2 f = __half22float2(hp[p]);
            if (BN) {
                f.x = fmaxf(fmaf(f.x, sc[2 * p + 0], sh[2 * p + 0]), 0.f);
                f.y = fmaxf(fmaf(f.y, sc[2 * p + 1], sh[2 * p + 1]), 0.f);
            }
            acc[2 * p + 0] = f.x * d2;
            acc[2 * p + 1] = f.y * d2;
        }
        if (BIAS) {
            float bv[8];
            *reinterpret_cast<float4*>(&bv[0]) = *reinterpret_cast<const float4*>(&bias[c0]);
            *reinterpret_cast<float4*>(&bv[4]) = *reinterpret_cast<const float4*>(&bias[c0 + 4]);
#pragma unroll
            for (int j = 0; j < 8; j++) acc[j] += bv[j];
        }
    }

    int s = row_start[n], len = counts[n];
    int i = 0;
    for (; i + 8 <= len; i += 8) {
        int2 e0 = csr[s + i + slot];
        int2 e1 = csr[s + i + 4 + slot];
        uint4 r0 = *reinterpret_cast<const uint4*>(&h[(size_t)e0.x * 128 + c0]);
        uint4 r1 = *reinterpret_cast<const uint4*>(&h[(size_t)e1.x * 128 + c0]);
        accum8<BN>(acc, r0, __int_as_float(e0.y), sc, sh);
        accum8<BN>(acc, r1, __int_as_float(e1.y), sc, sh);
    }
    if (i < len) {   // masked tail: idx 0 / weight 0 (h[0] is valid memory)
        int i0 = i + slot, i1 = i + 4 + slot;
        int2 e0 = (i0 < len) ? csr[s + i0] : make_int2(0, 0);
        int2 e1 = (i1 < len) ? csr[s + i1] : make_int2(0, 0);
        uint4 r0 = *reinterpret_cast<const uint4*>(&h[(size_t)e0.x * 128 + c0]);
        uint4 r1 = *reinterpret_cast<const uint4*>(&h[(size_t)e1.x * 128 + c0]);
        accum8<BN>(acc, r0, __int_as_float(e0.y), sc, sh);
        accum8<BN>(acc, r1, __int_as_float(e1.y), sc, sh);
    }

    // combine 4 slots; all lanes end with the full sum
#pragma unroll
    for (int j = 0; j < 8; j++) {
        acc[j] += __shfl_xor(acc[j], 16);
        acc[j] += __shfl_xor(acc[j], 32);
    }
    if (slot == 0) {
        *reinterpret_cast<float4*>(&out[(size_t)n * 128 + c0]) =
            make_float4(acc[0], acc[1], acc[2], acc[3]);
        *reinterpret_cast<float4*>(&out[(size_t)n * 128 + c0 + 4]) =
            make_float4(acc[4], acc[5], acc[6], acc[7]);
        if (W16) {
            __half hv[8] __attribute__((aligned(16)));
#pragma unroll
            for (int j = 0; j < 8; j++) hv[j] = __float2half_rn(acc[j]);
            *reinterpret_cast<uint4*>(&out16[(size_t)n * 128 + c0]) =
                *reinterpret_cast<const uint4*>(hv);
        }
    }
}

// ---------------- BatchNorm statistics (float4 loads) ----------------

__global__ void k_zero_stats(double* __restrict__ colsum) {
    int t = threadIdx.x;
    if (t < 256) colsum[t] = 0.0;
}

__global__ __launch_bounds__(256) void k_stats(const float* __restrict__ buf,
                                               double* __restrict__ colsum) {
    int t = threadIdx.x;
    int cb = (t & 31) * 4;          // this thread's 4-column base (stride 256 == 0 mod 32)
    float4 s = make_float4(0.f, 0.f, 0.f, 0.f);
    float4 q = make_float4(0.f, 0.f, 0.f, 0.f);
    const float4* b4 = reinterpret_cast<const float4*>(buf);
    const long total4 = (long)NNODES * 32;
    for (long g = (long)blockIdx.x * 256 + t; g < total4; g += (long)gridDim.x * 256) {
        float4 v = b4[g];
        s.x += v.x; q.x += v.x * v.x;
        s.y += v.y; q.y += v.y * v.y;
        s.z += v.z; q.z += v.z * v.z;
        s.w += v.w; q.w += v.w * v.w;
    }
    __shared__ float ls[128][9];    // [col][group], pad 9 avoids bank conflicts
    __shared__ float lq[128][9];
    int grp = t >> 5;               // 8 groups of 32 threads share each col-base
    ls[cb + 0][grp] = s.x; lq[cb + 0][grp] = q.x;
    ls[cb + 1][grp] = s.y; lq[cb + 1][grp] = q.y;
    ls[cb + 2][grp] = s.z; lq[cb + 2][grp] = q.z;
    ls[cb + 3][grp] = s.w; lq[cb + 3][grp] = q.w;
    __syncthreads();
    if (t < 128) {
        double ds = 0.0, dq = 0.0;
#pragma unroll
        for (int j = 0; j < 8; j++) { ds += ls[t][j]; dq += lq[t][j]; }
        atomicAdd(&colsum[t], ds);
        atomicAdd(&colsum[128 + t], dq);
    }
}

__global__ void k_bn_finalize(const double* __restrict__ colsum, const float* __restrict__ g,
                              const float* __restrict__ be, float* __restrict__ scale,
                              float* __restrict__ shift) {
    int c = threadIdx.x;
    if (c >= 128) return;
    double mu = colsum[c] / (double)NNODES;
    double var = colsum[128 + c] / (double)NNODES - mu * mu;
    float sc = g[c] * (1.0f / sqrtf((float)var + EPSBN));
    scale[c] = sc;
    shift[c] = be[c] - (float)mu * sc;
}

// ---------------- launch ----------------

extern "C" void kernel_launch(void* const* d_in, const int* in_sizes, int n_in,
                              void* d_out, int out_size, void* d_ws, size_t ws_size,
                              hipStream_t stream) {
    const float* x  = (const float*)d_in[0];
    const int* ei   = (const int*)d_in[1];
    const float* W1 = (const float*)d_in[2];
    const float* b1 = (const float*)d_in[3];
    const float* g1 = (const float*)d_in[4];
    const float* be1 = (const float*)d_in[5];
    const float* W2 = (const float*)d_in[6];
    const float* b2 = (const float*)d_in[7];
    const float* g2 = (const float*)d_in[8];
    const float* be2 = (const float*)d_in[9];
    const float* Wf = (const float*)d_in[10];
    const float* bf = (const float*)d_in[11];
    float* out = (float*)d_out;

    char* ws = (char*)d_ws;
    int*    counts    = (int*)(ws + 0);
    int*    row_start = (int*)(ws + 512ull * 1024);
    int*    cursor    = (int*)(ws + 1024ull * 1024);
    float*  dinv      = (float*)(ws + 1536ull * 1024);
    int*    blockSums = (int*)(ws + 2048ull * 1024);
    double* colsum    = (double*)(ws + 2304ull * 1024);
    float*  scale     = (float*)(ws + 2368ull * 1024);
    float*  shift     = (float*)(ws + 2372ull * 1024);
    int*    bcur      = (int*)(ws + 2400ull * 1024);          // 16 KB
    int2*   csr       = (int2*)(ws + 3ull * 1024 * 1024);     // 12.8 MB
    __half* h16       = (__half*)(ws + 16ull * 1024 * 1024);  // 25.6 MB (h1, then h2)
    __half* z16       = (__half*)(ws + 42ull * 1024 * 1024);  // 25.6 MB (raw z2 copy)
    float*  zbuf      = (float*)(ws + 68ull * 1024 * 1024);   // 51.2 MB (z1 -> z2 -> a3)
    int2*   tmp       = (int2*)(ws + 68ull * 1024 * 1024);    // aliases zbuf (dead before agg1)

    const int NB_N = (NNODES + 255) / 256;     // 391
    const int NB_E = (NEDGES + 255) / 256;     // 6250
    const int NB_G = (NNODES + 63) / 64;       // 1563 (gemm)
    const int NB_A = (NNODES + 3) / 4;         // 25000 (agg)
    const int NB_B = (FB_NB + 255) / 256;      // 2

    // CSR build (counting-sort: private write ranges -> ~1x write amplification)
    hipLaunchKernelGGL(k_zero_counts, dim3(NB_N), dim3(256), 0, stream, counts);
    hipLaunchKernelGGL(k_count, dim3(NB_E), dim3(256), 0, stream, ei, counts);
    hipLaunchKernelGGL(k_dinv, dim3(NB_N), dim3(256), 0, stream, counts, dinv);
    hipLaunchKernelGGL(k_scan1, dim3(NB_N), dim3(256), 0, stream, counts, row_start, blockSums);
    hipLaunchKernelGGL(k_scan2, dim3(1), dim3(512), 0, stream, blockSums, NB_N);
    hipLaunchKernelGGL(k_scan3, dim3(NB_N), dim3(256), 0, stream, row_start, blockSums, cursor);
    hipLaunchKernelGGL(k_binit, dim3(NB_B), dim3(256), 0, stream, row_start, bcur);
    hipLaunchKernelGGL(k_fillA, dim3(256), dim3(256), 0, stream, ei, bcur, tmp);
    hipLaunchKernelGGL(k_fillB, dim3(FB_NB), dim3(256), 0, stream, tmp, row_start, dinv, csr);

    // conv1: gemm (fp16 out) + aggregate(+b1) -> z1 (fp32)
    hipLaunchKernelGGL((k_gemm128<false>), dim3(NB_G), dim3(256), 0, stream,
                       x, W1, h16, (const float*)nullptr, (const float*)nullptr);
    hipLaunchKernelGGL((k_aggh<false, true, false>), dim3(NB_A), dim3(256), 0, stream,
                       h16, dinv, row_start, counts, csr, b1,
                       (const float*)nullptr, (const float*)nullptr, zbuf, (__half*)nullptr);
    // BN1 stats over z1
    hipLaunchKernelGGL(k_zero_stats, dim3(1), dim3(256), 0, stream, colsum);
    hipLaunchKernelGGL(k_stats, dim3(1024), dim3(256), 0, stream, zbuf, colsum);
    hipLaunchKernelGGL(k_bn_finalize, dim3(1), dim3(128), 0, stream, colsum, g1, be1, scale, shift);

    // conv2: gemm (BN1+ReLU fused on A-load, fp16 out) + aggregate(+b2) -> z2 (fp32 + fp16 raw)
    hipLaunchKernelGGL((k_gemm128<true>), dim3(NB_G), dim3(256), 0, stream,
                       zbuf, W2, h16, scale, shift);
    hipLaunchKernelGGL((k_aggh<false, true, true>), dim3(NB_A), dim3(256), 0, stream,
                       h16, dinv, row_start, counts, csr, b2,
                       (const float*)nullptr, (const float*)nullptr, zbuf, z16);
    // BN2 stats over z2
    hipLaunchKernelGGL(k_zero_stats, dim3(1), dim3(256), 0, stream, colsum);
    hipLaunchKernelGGL(k_stats, dim3(1024), dim3(256), 0, stream, zbuf, colsum);
    hipLaunchKernelGGL(k_bn_finalize, dim3(1), dim3(128), 0, stream, colsum, g2, be2, scale, shift);

    // conv3 restructured: agg(act2) first (BN2+ReLU fused on fp16 gather), then GEMM->40+lsm.
    // agg(act @ Wf) == agg(act) @ Wf since aggregation is linear.
    hipLaunchKernelGGL((k_aggh<true, false, false>), dim3(NB_A), dim3(256), 0, stream,
                       z16, dinv, row_start, counts, csr, (const float*)nullptr,
                       scale, shift, zbuf, (__half*)nullptr);
    hipLaunchKernelGGL(k_gemm40_lsm, dim3(NB_G), dim3(256), 0, stream, zbuf, Wf, bf, out);
}

// Round 9
// 616.254 us; speedup vs baseline: 1.2579x; 1.0218x over previous
//
#include <hip/hip_runtime.h>
#include <hip/hip_bf16.h>
#include <hip/hip_fp16.h>
#include <math.h>

// Problem constants (match reference)
#define NNODES 100000
#define NEDGES 1600000
#define DH 128
#define DOUT 40
#define EPSBN 1e-5f
// counting-sort fill: bucket = dst >> FB_SH (256 nodes/bucket)
#define FB_SH 8
#define FB_NB ((NNODES + 255) >> 8)   // 391 buckets

// ---------------- degree / CSR build ----------------

__global__ void k_zero_counts(int* __restrict__ counts) {
    int i = blockIdx.x * blockDim.x + threadIdx.x;
    if (i < NNODES) counts[i] = 0;
}

__global__ void k_count(const int* __restrict__ ei, int* __restrict__ counts) {
    int e = blockIdx.x * blockDim.x + threadIdx.x;
    if (e < NEDGES) atomicAdd(&counts[ei[NEDGES + e]], 1);
}

__global__ void k_dinv(const int* __restrict__ counts, float* __restrict__ dinv) {
    int i = blockIdx.x * blockDim.x + threadIdx.x;
    if (i < NNODES) dinv[i] = 1.0f / sqrtf((float)counts[i] + 1.0f);
}

// per-block exclusive scan of counts -> row_start, block totals -> blockSums
__global__ void k_scan1(const int* __restrict__ counts, int* __restrict__ row_start,
                        int* __restrict__ blockSums) {
    __shared__ int s[256];
    int t = threadIdx.x;
    int g = blockIdx.x * 256 + t;
    int v = (g < NNODES) ? counts[g] : 0;
    s[t] = v;
    __syncthreads();
    for (int off = 1; off < 256; off <<= 1) {
        int x = (t >= off) ? s[t - off] : 0;
        __syncthreads();
        s[t] += x;
        __syncthreads();
    }
    if (g < NNODES) row_start[g] = s[t] - v;   // exclusive
    if (t == 255) blockSums[blockIdx.x] = s[255];
}

__global__ void k_scan2(int* __restrict__ blockSums, int nb) {
    __shared__ int s[512];
    int t = threadIdx.x;
    int v = (t < nb) ? blockSums[t] : 0;
    s[t] = v;
    __syncthreads();
    for (int off = 1; off < 512; off <<= 1) {
        int x = (t >= off) ? s[t - off] : 0;
        __syncthreads();
        s[t] += x;
        __syncthreads();
    }
    if (t < nb) blockSums[t] = s[t] - v;       // exclusive
}

__global__ void k_scan3(int* __restrict__ row_start, const int* __restrict__ blockSums,
                        int* __restrict__ cursor) {
    int g = blockIdx.x * 256 + threadIdx.x;
    if (g < NNODES) {
        int r = row_start[g] + blockSums[blockIdx.x];
        row_start[g] = r;
        cursor[g] = r;
    }
}

// bucket cursors: bucket b's tmp region starts at row_start[b << FB_SH]
__global__ void k_binit(const int* __restrict__ row_start, int* __restrict__ bcur) {
    int b = blockIdx.x * 256 + threadIdx.x;
    if (b < FB_NB) bcur[b] = row_start[b << FB_SH];
}

// fill pass A: each WG owns a contiguous edge chunk. Count per bucket in LDS,
// reserve ONE contiguous private range per (WG,bucket), then scatter {src,dst}
// into it. Private ranges -> lines written by a single XCD -> ~1x write amp.
__global__ __launch_bounds__(256) void k_fillA(const int* __restrict__ ei,
                                               int* __restrict__ bcur,
                                               int2* __restrict__ tmp) {
    __shared__ int lcnt[FB_NB];
    __shared__ int lbase[FB_NB];
    int t = threadIdx.x;
    const int chunk = (NEDGES + gridDim.x - 1) / gridDim.x;
    int e0 = blockIdx.x * chunk;
    int e1 = min(e0 + chunk, NEDGES);
    for (int i = t; i < FB_NB; i += 256) lcnt[i] = 0;
    __syncthreads();
    for (int e = e0 + t; e < e1; e += 256)
        atomicAdd(&lcnt[ei[NEDGES + e] >> FB_SH], 1);
    __syncthreads();
    for (int b = t; b < FB_NB; b += 256) {
        int c = lcnt[b];
        lbase[b] = c ? atomicAdd(&bcur[b], c) : 0;
    }
    __syncthreads();
    for (int i = t; i < FB_NB; i += 256) lcnt[i] = 0;
    __syncthreads();
    for (int e = e0 + t; e < e1; e += 256) {
        int src = ei[e];
        int dst = ei[NEDGES + e];
        int b = dst >> FB_SH;
        int r = atomicAdd(&lcnt[b], 1);
        tmp[lbase[b] + r] = make_int2(src, dst);
    }
}

// fill pass B: ONE WG per bucket. Sequential read of the bucket's tmp region;
// exact-dst rank via LDS counters (all of this bucket's edges are here, so the
// LDS rank is globally correct -- no global atomics). Scatter stays within the
// bucket's ~32KB csr region on one XCD.
__global__ __launch_bounds__(256) void k_fillB(const int2* __restrict__ tmp,
                                               const int* __restrict__ row_start,
                                               const float* __restrict__ dinv,
                                               int2* __restrict__ csr) {
    __shared__ int lrank[1 << FB_SH];
    int t = threadIdx.x;
    int b = blockIdx.x;
    int n0 = b << FB_SH;
    int s = row_start[n0];
    int e = (((b + 1) << FB_SH) >= NNODES) ? NEDGES : row_start[(b + 1) << FB_SH];
    for (int i = t; i < (1 << FB_SH); i += 256) lrank[i] = 0;
    __syncthreads();
    for (int i = s + t; i < e; i += 256) {
        int2 sd = tmp[i];
        float w = dinv[sd.x] * dinv[sd.y];
        int r = atomicAdd(&lrank[sd.y - n0], 1);
        csr[row_start[sd.y] + r] = make_int2(sd.x, __float_as_int(w));
    }
}

// ---------------- GEMM: out16[N][128] = act(A)[N][128] @ W[128][128] ----------------
// AHALF: A is fp16 (BN/ReLU applied on load when BN). !AHALF: A fp32, no BN.

template <bool BN, bool AHALF>
__global__ __launch_bounds__(256) void k_gemm128(const void* __restrict__ Av,
                                                 const float* __restrict__ W,
                                                 __half* __restrict__ out,
                                                 const float* __restrict__ scale,
                                                 const float* __restrict__ shift) {
    const int BM = 64, BK = 32;
    __shared__ float As[BK][68];
    __shared__ float Bs[BK][128];
    int t = threadIdx.x;
    int tx = t & 15, ty = t >> 4;
    int r0 = blockIdx.x * BM;

    float acc[4][8];
#pragma unroll
    for (int i = 0; i < 4; i++)
#pragma unroll
        for (int j = 0; j < 8; j++) acc[i][j] = 0.0f;

    for (int k0 = 0; k0 < 128; k0 += BK) {
        if (AHALF) {
            const __half* A = (const __half*)Av;
            int row = t >> 2;            // 0..63
            int c8 = (t & 3) * 8;        // 0,8,16,24
            int gr = r0 + row;
            uint4 raw = make_uint4(0, 0, 0, 0);
            if (gr < NNODES)
                raw = *reinterpret_cast<const uint4*>(&A[(size_t)gr * 128 + k0 + c8]);
            const __half2* hp = reinterpret_cast<const __half2*>(&raw);
#pragma unroll
            for (int p = 0; p < 4; p++) {
                float2 f = __half22float2(hp[p]);
                if (BN) {
                    int kc = k0 + c8 + 2 * p;
                    f.x = fmaxf(fmaf(f.x, scale[kc + 0], shift[kc + 0]), 0.f);
                    f.y = fmaxf(fmaf(f.y, scale[kc + 1], shift[kc + 1]), 0.f);
                }
                As[c8 + 2 * p + 0][row] = f.x;
                As[c8 + 2 * p + 1][row] = f.y;
            }
        } else {
            const float* A = (const float*)Av;
#pragma unroll
            for (int u = 0; u < 2; u++) {
                int idx = t + u * 256;
                int row = idx >> 3, c4 = idx & 7;
                int gr = r0 + row;
                float4 v = make_float4(0.f, 0.f, 0.f, 0.f);
                if (gr < NNODES)
                    v = *reinterpret_cast<const float4*>(&A[(size_t)gr * 128 + k0 + c4 * 4]);
                As[c4 * 4 + 0][row] = v.x;
                As[c4 * 4 + 1][row] = v.y;
                As[c4 * 4 + 2][row] = v.z;
                As[c4 * 4 + 3][row] = v.w;
            }
        }
#pragma unroll
        for (int u = 0; u < 4; u++) {
            int idx = t + u * 256;
            int k = idx >> 5, c4 = idx & 31;
            *reinterpret_cast<float4*>(&Bs[k][c4 * 4]) =
                *reinterpret_cast<const float4*>(&W[(size_t)(k0 + k) * 128 + c4 * 4]);
        }
        __syncthreads();
#pragma unroll
        for (int k = 0; k < BK; k++) {
            float a[4];
            *reinterpret_cast<float4*>(a) = *reinterpret_cast<const float4*>(&As[k][ty * 4]);
            float b[8];
#pragma unroll
            for (int j = 0; j < 8; j++) b[j] = Bs[k][tx * 8 + j];
#pragma unroll
            for (int i = 0; i < 4; i++)
#pragma unroll
                for (int j = 0; j < 8; j++) acc[i][j] = fmaf(a[i], b[j], acc[i][j]);
        }
        __syncthreads();
    }
#pragma unroll
    for (int i = 0; i < 4; i++) {
        int gr = r0 + ty * 4 + i;
        if (gr >= NNODES) continue;
        __half hv[8] __attribute__((aligned(16)));
#pragma unroll
        for (int j = 0; j < 8; j++) hv[j] = __float2half_rn(acc[i][j]);
        *reinterpret_cast<uint4*>(&out[(size_t)gr * 128 + tx * 8]) =
            *reinterpret_cast<const uint4*>(hv);
    }
}

// ---------------- GEMM 128->40 (fp16 in) with bias + log_softmax epilogue -------

__global__ __launch_bounds__(256) void k_gemm40_lsm(const __half* __restrict__ A,
                                                    const float* __restrict__ W,
                                                    const float* __restrict__ bias,
                                                    float* __restrict__ out) {
    const int BM = 64, BK = 32;
    __shared__ float As[BK][68];
    __shared__ float Bs[BK][48];
    int t = threadIdx.x;
    int tx = t & 15, ty = t >> 4;
    int r0 = blockIdx.x * BM;

    float acc[4][3];
#pragma unroll
    for (int i = 0; i < 4; i++)
#pragma unroll
        for (int j = 0; j < 3; j++) acc[i][j] = 0.0f;

    for (int k0 = 0; k0 < 128; k0 += BK) {
        {
            int row = t >> 2;
            int c8 = (t & 3) * 8;
            int gr = r0 + row;
            uint4 raw = make_uint4(0, 0, 0, 0);
            if (gr < NNODES)
                raw = *reinterpret_cast<const uint4*>(&A[(size_t)gr * 128 + k0 + c8]);
            const __half2* hp = reinterpret_cast<const __half2*>(&raw);
#pragma unroll
            for (int p = 0; p < 4; p++) {
                float2 f = __half22float2(hp[p]);
                As[c8 + 2 * p + 0][row] = f.x;
                As[c8 + 2 * p + 1][row] = f.y;
            }
        }
        for (int idx = t; idx < BK * 48; idx += 256) {
            int k = idx / 48, c = idx % 48;
            Bs[k][c] = (c < DOUT) ? W[(size_t)(k0 + k) * DOUT + c] : 0.f;
        }
        __syncthreads();
#pragma unroll
        for (int k = 0; k < BK; k++) {
            float a[4];
            *reinterpret_cast<float4*>(a) = *reinterpret_cast<const float4*>(&As[k][ty * 4]);
            float b[3];
#pragma unroll
            for (int j = 0; j < 3; j++) b[j] = Bs[k][tx * 3 + j];
#pragma unroll
            for (int i = 0; i < 4; i++)
#pragma unroll
                for (int j = 0; j < 3; j++) acc[i][j] = fmaf(a[i], b[j], acc[i][j]);
        }
        __syncthreads();
    }
    // epilogue: +bias, then per-row log_softmax (row split across 16 lanes of same ty)
#pragma unroll
    for (int i = 0; i < 4; i++) {
        int gr = r0 + ty * 4 + i;
        float v[3];
        float m = -1e30f;
#pragma unroll
        for (int j = 0; j < 3; j++) {
            int c = tx * 3 + j;
            v[j] = (c < DOUT) ? acc[i][j] + bias[c] : -1e30f;
            m = fmaxf(m, v[j]);
        }
#pragma unroll
        for (int off = 8; off; off >>= 1) m = fmaxf(m, __shfl_xor(m, off));
        float es = 0.f;
#pragma unroll
        for (int j = 0; j < 3; j++)
            if (tx * 3 + j < DOUT) es += expf(v[j] - m);
#pragma unroll
        for (int off = 8; off; off >>= 1) es += __shfl_xor(es, off);
        float lse = m + logf(es);
        if (gr < NNODES) {
#pragma unroll
            for (int j = 0; j < 3; j++) {
                int c = tx * 3 + j;
                if (c < DOUT) out[(size_t)gr * DOUT + c] = v[j] - lse;
            }
        }
    }
}

// ---------------- aggregation (pull via CSR), fp16 rows, fp16 out ----------------
// One wave per dst row. 4 edge slots (16 lanes each); each lane loads uint4 =
// 8 halves (16B) -> 16 lanes cover the 256B fp16 row. 8 edges in flight per
// iteration (2 per slot). Quarter-wave results combined via shfl_xor(16|32).
// out16[n] = fp16( act(h[n])*dinv^2 + (bias) + sum act(h[src])*w )

template <bool BN>
__device__ __forceinline__ void accum8(float (&acc)[8], uint4 raw, float w,
                                       const float (&sc)[8], const float (&sh)[8]) {
    const __half2* hp = reinterpret_cast<const __half2*>(&raw);
#pragma unroll
    for (int p = 0; p < 4; p++) {
        float2 f = __half22float2(hp[p]);
        if (BN) {
            f.x = fmaxf(fmaf(f.x, sc[2 * p + 0], sh[2 * p + 0]), 0.f);
            f.y = fmaxf(fmaf(f.y, sc[2 * p + 1], sh[2 * p + 1]), 0.f);
        }
        acc[2 * p + 0] = fmaf(f.x, w, acc[2 * p + 0]);
        acc[2 * p + 1] = fmaf(f.y, w, acc[2 * p + 1]);
    }
}

template <bool BN, bool BIAS>
__global__ __launch_bounds__(256) void k_aggh(const __half* __restrict__ h,
                                              const float* __restrict__ dinv,
                                              const int* __restrict__ row_start,
                                              const int* __restrict__ counts,
                                              const int2* __restrict__ csr,
                                              const float* __restrict__ bias,
                                              const float* __restrict__ scale,
                                              const float* __restrict__ shift,
                                              __half* __restrict__ out16) {
    int wid = threadIdx.x >> 6, lane = threadIdx.x & 63;
    int n = blockIdx.x * 4 + wid;
    if (n >= NNODES) return;
    int slot = lane >> 4;          // 0..3 edge slot
    int c0 = (lane & 15) * 8;      // this lane's 8-column base

    float sc[8], sh[8];
    if (BN) {
        *reinterpret_cast<float4*>(&sc[0]) = *reinterpret_cast<const float4*>(&scale[c0]);
        *reinterpret_cast<float4*>(&sc[4]) = *reinterpret_cast<const float4*>(&scale[c0 + 4]);
        *reinterpret_cast<float4*>(&sh[0]) = *reinterpret_cast<const float4*>(&shift[c0]);
        *reinterpret_cast<float4*>(&sh[4]) = *reinterpret_cast<const float4*>(&shift[c0 + 4]);
    }

    float acc[8];
#pragma unroll
    for (int j = 0; j < 8; j++) acc[j] = 0.f;

    // self-loop term on slot 0
    if (slot == 0) {
        float di = dinv[n];
        float d2 = di * di;
        uint4 raw = *reinterpret_cast<const uint4*>(&h[(size_t)n * 128 + c0]);
        const __half2* hp = reinterpret_cast<const __half2*>(&raw);
#pragma unroll
        for (int p = 0; p < 4; p++) {
            float2 f = __half22float2(hp[p]);
            if (BN) {
                f.x = fmaxf(fmaf(f.x, sc[2 * p + 0], sh[2 * p + 0]), 0.f);
                f.y = fmaxf(fmaf(f.y, sc[2 * p + 1], sh[2 * p + 1]), 0.f);
            }
            acc[2 * p + 0] = f.x * d2;
            acc[2 * p + 1] = f.y * d2;
        }
        if (BIAS) {
            float bv[8];
            *reinterpret_cast<float4*>(&bv[0]) = *reinterpret_cast<const float4*>(&bias[c0]);
            *reinterpret_cast<float4*>(&bv[4]) = *reinterpret_cast<const float4*>(&bias[c0 + 4]);
#pragma unroll
            for (int j = 0; j < 8; j++) acc[j] += bv[j];
        }
    }

    int s = row_start[n], len = counts[n];
    int i = 0;
    for (; i + 8 <= len; i += 8) {
        int2 e0 = csr[s + i + slot];
        int2 e1 = csr[s + i + 4 + slot];
        uint4 r0 = *reinterpret_cast<const uint4*>(&h[(size_t)e0.x * 128 + c0]);
        uint4 r1 = *reinterpret_cast<const uint4*>(&h[(size_t)e1.x * 128 + c0]);
        accum8<BN>(acc, r0, __int_as_float(e0.y), sc, sh);
        accum8<BN>(acc, r1, __int_as_float(e1.y), sc, sh);
    }
    if (i < len) {   // masked tail: idx 0 / weight 0 (h[0] is valid memory)
        int i0 = i + slot, i1 = i + 4 + slot;
        int2 e0 = (i0 < len) ? csr[s + i0] : make_int2(0, 0);
        int2 e1 = (i1 < len) ? csr[s + i1] : make_int2(0, 0);
        uint4 r0 = *reinterpret_cast<const uint4*>(&h[(size_t)e0.x * 128 + c0]);
        uint4 r1 = *reinterpret_cast<const uint4*>(&h[(size_t)e1.x * 128 + c0]);
        accum8<BN>(acc, r0, __int_as_float(e0.y), sc, sh);
        accum8<BN>(acc, r1, __int_as_float(e1.y), sc, sh);
    }

    // combine 4 slots; all lanes end with the full sum
#pragma unroll
    for (int j = 0; j < 8; j++) {
        acc[j] += __shfl_xor(acc[j], 16);
        acc[j] += __shfl_xor(acc[j], 32);
    }
    if (slot == 0) {
        __half hv[8] __attribute__((aligned(16)));
#pragma unroll
        for (int j = 0; j < 8; j++) hv[j] = __float2half_rn(acc[j]);
        *reinterpret_cast<uint4*>(&out16[(size_t)n * 128 + c0]) =
            *reinterpret_cast<const uint4*>(hv);
    }
}

// ---------------- BatchNorm statistics (fp16 input, uint4 loads) ----------------

__global__ void k_zero_stats(double* __restrict__ colsum) {
    int t = threadIdx.x;
    if (t < 256) colsum[t] = 0.0;
}

__global__ __launch_bounds__(256) void k_stats16(const __half* __restrict__ buf,
                                                 double* __restrict__ colsum) {
    int t = threadIdx.x;
    int cb = (t & 15) * 8;          // this thread's 8-column base (grid stride == 0 mod 16)
    float s[8], q[8];
#pragma unroll
    for (int j = 0; j < 8; j++) { s[j] = 0.f; q[j] = 0.f; }
    const uint4* b4 = reinterpret_cast<const uint4*>(buf);
    const long total4 = (long)NNODES * 16;   // 16 uint4 per 128-col row
    for (long g = (long)blockIdx.x * 256 + t; g < total4; g += (long)gridDim.x * 256) {
        uint4 v = b4[g];
        const __half2* hp = reinterpret_cast<const __half2*>(&v);
#pragma unroll
        for (int p = 0; p < 4; p++) {
            float2 f = __half22float2(hp[p]);
            s[2 * p + 0] += f.x; q[2 * p + 0] += f.x * f.x;
            s[2 * p + 1] += f.y; q[2 * p + 1] += f.y * f.y;
        }
    }
    __shared__ float ls[128][17];   // [col][group], pad 17 avoids bank conflicts
    __shared__ float lq[128][17];
    int grp = t >> 4;               // 16 groups of 16 threads share each col-base
#pragma unroll
    for (int j = 0; j < 8; j++) {
        ls[cb + j][grp] = s[j];
        lq[cb + j][grp] = q[j];
    }
    __syncthreads();
    if (t < 128) {
        double ds = 0.0, dq = 0.0;
#pragma unroll
        for (int j = 0; j < 16; j++) { ds += ls[t][j]; dq += lq[t][j]; }
        atomicAdd(&colsum[t], ds);
        atomicAdd(&colsum[128 + t], dq);
    }
}

__global__ void k_bn_finalize(const double* __restrict__ colsum, const float* __restrict__ g,
                              const float* __restrict__ be, float* __restrict__ scale,
                              float* __restrict__ shift) {
    int c = threadIdx.x;
    if (c >= 128) return;
    double mu = colsum[c] / (double)NNODES;
    double var = colsum[128 + c] / (double)NNODES - mu * mu;
    float sc = g[c] * (1.0f / sqrtf((float)var + EPSBN));
    scale[c] = sc;
    shift[c] = be[c] - (float)mu * sc;
}

// ---------------- launch ----------------

extern "C" void kernel_launch(void* const* d_in, const int* in_sizes, int n_in,
                              void* d_out, int out_size, void* d_ws, size_t ws_size,
                              hipStream_t stream) {
    const float* x  = (const float*)d_in[0];
    const int* ei   = (const int*)d_in[1];
    const float* W1 = (const float*)d_in[2];
    const float* b1 = (const float*)d_in[3];
    const float* g1 = (const float*)d_in[4];
    const float* be1 = (const float*)d_in[5];
    const float* W2 = (const float*)d_in[6];
    const float* b2 = (const float*)d_in[7];
    const float* g2 = (const float*)d_in[8];
    const float* be2 = (const float*)d_in[9];
    const float* Wf = (const float*)d_in[10];
    const float* bf = (const float*)d_in[11];
    float* out = (float*)d_out;

    char* ws = (char*)d_ws;
    int*    counts    = (int*)(ws + 0);
    int*    row_start = (int*)(ws + 512ull * 1024);
    int*    cursor    = (int*)(ws + 1024ull * 1024);
    float*  dinv      = (float*)(ws + 1536ull * 1024);
    int*    blockSums = (int*)(ws + 2048ull * 1024);
    double* colsum    = (double*)(ws + 2304ull * 1024);
    float*  scale     = (float*)(ws + 2368ull * 1024);
    float*  shift     = (float*)(ws + 2372ull * 1024);
    int*    bcur      = (int*)(ws + 2400ull * 1024);          // 16 KB
    int2*   csr       = (int2*)(ws + 3ull * 1024 * 1024);     // 12.8 MB
    __half* h16       = (__half*)(ws + 16ull * 1024 * 1024);  // 25.6 MB (h1, then h2)
    __half* zA        = (__half*)(ws + 42ull * 1024 * 1024);  // 25.6 MB (z1)
    __half* zB        = (__half*)(ws + 68ull * 1024 * 1024);  // 25.6 MB (z2)
    __half* a16       = (__half*)(ws + 94ull * 1024 * 1024);  // 25.6 MB (agg3 out)
    int2*   tmp       = (int2*)(ws + 42ull * 1024 * 1024);    // aliases zA (dead before agg1)

    const int NB_N = (NNODES + 255) / 256;     // 391
    const int NB_E = (NEDGES + 255) / 256;     // 6250
    const int NB_G = (NNODES + 63) / 64;       // 1563 (gemm)
    const int NB_A = (NNODES + 3) / 4;         // 25000 (agg)
    const int NB_B = (FB_NB + 255) / 256;      // 2

    // CSR build (counting-sort: private write ranges -> ~1x write amplification)
    hipLaunchKernelGGL(k_zero_counts, dim3(NB_N), dim3(256), 0, stream, counts);
    hipLaunchKernelGGL(k_count, dim3(NB_E), dim3(256), 0, stream, ei, counts);
    hipLaunchKernelGGL(k_dinv, dim3(NB_N), dim3(256), 0, stream, counts, dinv);
    hipLaunchKernelGGL(k_scan1, dim3(NB_N), dim3(256), 0, stream, counts, row_start, blockSums);
    hipLaunchKernelGGL(k_scan2, dim3(1), dim3(512), 0, stream, blockSums, NB_N);
    hipLaunchKernelGGL(k_scan3, dim3(NB_N), dim3(256), 0, stream, row_start, blockSums, cursor);
    hipLaunchKernelGGL(k_binit, dim3(NB_B), dim3(256), 0, stream, row_start, bcur);
    hipLaunchKernelGGL(k_fillA, dim3(256), dim3(256), 0, stream, ei, bcur, tmp);
    hipLaunchKernelGGL(k_fillB, dim3(FB_NB), dim3(256), 0, stream, tmp, row_start, dinv, csr);

    // conv1: gemm (fp32 A -> fp16 out) + aggregate(+b1) -> z1 fp16
    hipLaunchKernelGGL((k_gemm128<false, false>), dim3(NB_G), dim3(256), 0, stream,
                       (const void*)x, W1, h16, (const float*)nullptr, (const float*)nullptr);
    hipLaunchKernelGGL((k_aggh<false, true>), dim3(NB_A), dim3(256), 0, stream,
                       h16, dinv, row_start, counts, csr, b1,
                       (const float*)nullptr, (const float*)nullptr, zA);
    // BN1 stats over z1 (fp16)
    hipLaunchKernelGGL(k_zero_stats, dim3(1), dim3(256), 0, stream, colsum);
    hipLaunchKernelGGL(k_stats16, dim3(1024), dim3(256), 0, stream, zA, colsum);
    hipLaunchKernelGGL(k_bn_finalize, dim3(1), dim3(128), 0, stream, colsum, g1, be1, scale, shift);

    // conv2: gemm (fp16 A, BN1+ReLU fused on load) + aggregate(+b2) -> z2 fp16
    hipLaunchKernelGGL((k_gemm128<true, true>), dim3(NB_G), dim3(256), 0, stream,
                       (const void*)zA, W2, h16, scale, shift);
    hipLaunchKernelGGL((k_aggh<false, true>), dim3(NB_A), dim3(256), 0, stream,
                       h16, dinv, row_start, counts, csr, b2,
                       (const float*)nullptr, (const float*)nullptr, zB);
    // BN2 stats over z2 (fp16)
    hipLaunchKernelGGL(k_zero_stats, dim3(1), dim3(256), 0, stream, colsum);
    hipLaunchKernelGGL(k_stats16, dim3(1024), dim3(256), 0, stream, zB, colsum);
    hipLaunchKernelGGL(k_bn_finalize, dim3(1), dim3(128), 0, stream, colsum, g2, be2, scale, shift);

    // conv3 restructured: agg(act2) first (BN2+ReLU fused on fp16 gather) -> a16,
    // then GEMM->40 + lsm.  agg(act @ Wf) == agg(act) @ Wf (aggregation is linear).
    hipLaunchKernelGGL((k_aggh<true, false>), dim3(NB_A), dim3(256), 0, stream,
                       zB, dinv, row_start, counts, csr, (const float*)nullptr,
                       scale, shift, a16);
    hipLaunchKernelGGL(k_gemm40_lsm, dim3(NB_G), dim3(256), 0, stream, a16, Wf, bf, out);
}